// Round 10
// baseline (301.306 us; speedup 1.0000x reference)
//
#include <hip/hip_runtime.h>

// GeometryTransformation: backproject(theta=0) -> 2x resblock(conv3d 16->16 3^3,
// InstanceNorm, ReLU, residual) -> forward-project at theta in {0, pi/2}.
//
// Round-10: proven r8 pipeline (x-constancy factorization: interior 2D field +
// width-16 boundary mini volume), dispatch count cut 11 -> 7:
//   prep_all_k : layer-0 state + weight prep (afrag/biasf/w2d) + zeroing, merged.
//   layer_k<0> : r8 layer_k verbatim (input read raw: vol0 or materialized xb).
//   layer_k<1> : input normalized ON THE FLY (no-residual InstanceNorm+ReLU) --
//                interior in staging, mini via lane-static column classification
//                REAL(mini raw->norm) / GHOST(interior->norm) / ZERO.
//   norm_k<1>  : kept only for xb = relu(IN(y2)+proj) (fproj needs it anyway).
//   fproj_k    : r8 fproj1 + per-d done-counter so the 2nd block per d expands
//                the theta=pi/2 outputs (old fproj2) in-dispatch.
// NO grid barriers (r9 lesson: co-residency not guaranteed -> spins timed out).
// Math identical to round-8 (passed, absmax 4.0).

typedef unsigned short u16;
typedef unsigned int   u32;
using s16x8 = __attribute__((ext_vector_type(8))) short;
using f32x4 = __attribute__((ext_vector_type(4))) float;

#define IN_ELEMS 262144        // 128*128*16 fp32 interior
#define MN_ELEMS 4194304       // 128*128*16*16 u16 mini
#define WS_NEED  56817472ull

__device__ __forceinline__ float bf2f(u16 h) {
    union { u32 u; float f; } v; v.u = ((u32)h) << 16; return v.f;
}
__device__ __forceinline__ u16 f2bf(float f) {
    union { float f; u32 u; } v; v.f = f;
    u32 u = v.u;
    return (u16)((u + 0x7fffu + ((u >> 16) & 1u)) >> 16);
}
__device__ __forceinline__ float ldin(const void* p, int i, int bf) {
    return bf ? bf2f(((const u16*)p)[i]) : ((const float*)p)[i];
}
__device__ __forceinline__ u16 ldbf(const void* p, int i, int bf) {
    return bf ? ((const u16*)p)[i] : f2bf(((const float*)p)[i]);
}
__device__ __forceinline__ void unpack8(uint4 a, float* f) {
    u32 w[4] = {a.x, a.y, a.z, a.w};
#pragma unroll
    for (int i = 0; i < 4; i++) {
        f[2*i]   = bf2f((u16)(w[i] & 0xffff));
        f[2*i+1] = bf2f((u16)(w[i] >> 16));
    }
}
__device__ __forceinline__ void unpack4(uint2 a, float* f) {
    f[0] = bf2f((u16)(a.x & 0xffff)); f[1] = bf2f((u16)(a.x >> 16));
    f[2] = bf2f((u16)(a.y & 0xffff)); f[3] = bf2f((u16)(a.y >> 16));
}
// normalize 8 channels + relu + pack to bf16 MFMA fragment
__device__ __forceinline__ s16x8 packnorm8(const float* f, const float* mv,
                                           const float* sv) {
    u32 pw[4];
#pragma unroll
    for (int j = 0; j < 4; j++) {
        float a = fmaxf((f[2*j]   - mv[2*j])   * sv[2*j],   0.f);
        float b = fmaxf((f[2*j+1] - mv[2*j+1]) * sv[2*j+1], 0.f);
        pw[j] = (u32)f2bf(a) | ((u32)f2bf(b) << 16);
    }
    return __builtin_bit_cast(s16x8, make_uint4(pw[0], pw[1], pw[2], pw[3]));
}

__global__ void sentinel_k(u16* __restrict__ out, int n)
{
    int i = blockIdx.x * 256 + threadIdx.x;
    if (i < n) out[i] = 0x4640;
}

// ---------------------------------------------------------------------------
// Merged prep: 647 blocks.
//  bid 0..511  : layer-0 state (interior I0 fp32 + mini M0, cols {0..4,7,8..11}
//                = proj, rest 0)
//  wb = bid-512:
//   0..17  : afrag[L][fi][lane][8]   (lane-ordered MFMA A operands)
//   18     : st zero + flag + biasf + dcnt zero
//   19..98 : zero P/PS/P0 (20480 floats contiguous from P)
//   99..134: w2d[L][tap9][ci][co] kx-summed fp32
// ---------------------------------------------------------------------------
__global__ __launch_bounds__(256) void prep_all_k(
    const void* __restrict__ proj,
    const void* __restrict__ w1, const void* __restrict__ w2,
    const void* __restrict__ w3, const void* __restrict__ w4,
    const void* __restrict__ b1, const void* __restrict__ b2,
    const void* __restrict__ b3, const void* __restrict__ b4,
    float* __restrict__ st, int* __restrict__ flag, float* __restrict__ biasf,
    float* __restrict__ w2d, float* __restrict__ pz, int* __restrict__ dcnt,
    u16* __restrict__ afrag, float* __restrict__ I0, u16* __restrict__ M0)
{
    const int tid = threadIdx.x;
    const u16* pp = (const u16*)w1;
    int cnt = 0;
    for (int i = 0; i < 32; i++) {
        int e = (pp[2 * i] >> 7) & 0xFF;
        if (e >= 64 && e <= 130) cnt++;
    }
    const int bf = (cnt >= 24) ? 1 : 0;

    if (blockIdx.x < 512) {
        const int d = blockIdx.x >> 2;
        const int ys = (blockIdx.x & 3) * 32;
        for (int i = tid; i < 512; i += 256) {
            int y = ys + (i >> 4), c = i & 15;
            I0[(d * 128 + y) * 16 + c] = ldin(proj, c * 16384 + d * 128 + y, bf);
        }
        for (int i = tid; i < 1024; i += 256) {
            int y = ys + (i >> 5), x = (i >> 1) & 15, hh = i & 1;
            bool on = (x <= 4) | (x == 7) | (x >= 8 && x < 12);
            u32 pw[4] = {0u, 0u, 0u, 0u};
            if (on) {
#pragma unroll
                for (int j = 0; j < 4; j++) {
                    int c0 = hh * 8 + 2 * j;
                    u16 a = f2bf(ldin(proj, c0 * 16384 + d * 128 + y, bf));
                    u16 b = f2bf(ldin(proj, (c0 + 1) * 16384 + d * 128 + y, bf));
                    pw[j] = (u32)a | ((u32)b << 16);
                }
            }
            *(uint4*)(M0 + ((d * 128 + y) << 8) + (x << 4) + hh * 8) =
                make_uint4(pw[0], pw[1], pw[2], pw[3]);
        }
        return;
    }

    const void* WS[4] = {w1, w2, w3, w4};
    const void* BS[4] = {b1, b2, b3, b4};
    const int wb = blockIdx.x - 512;
    if (wb < 18) {
        int gi = wb * 256 + tid;              // < 4608
        int L = gi / 1152, r = gi - L * 1152;
        int fi = r >> 6, l = r & 63;
        int kzky = fi >> 1, grp = fi & 1;
        int kz = kzky / 3, ky = kzky % 3;
        int n = l & 15, g = l >> 4, h = g & 1, kxs = g >> 1;
        int kx = grp * 2 + kxs;
        u16 v[8];
#pragma unroll
        for (int e = 0; e < 8; e++) {
            int ci = h * 8 + e;
            v[e] = (kx <= 2) ? ldbf(WS[L], n * 432 + ci * 27 + kz * 9 + ky * 3 + kx, bf)
                             : (u16)0;
        }
#pragma unroll
        for (int e = 0; e < 8; e++) afrag[gi * 8 + e] = v[e];
    } else if (wb == 18) {
        st[tid] = 0.f;
        if (tid == 0) *flag = bf;
        if (tid < 64) biasf[tid] = ldin(BS[tid >> 4], tid & 15, bf);
        if (tid < 128) dcnt[tid] = 0;
    } else if (wb < 99) {
        int i = (wb - 19) * 256 + tid;        // P(16384)+PS(2048)+P0(2048)
        pz[i] = 0.f;
    } else {
        int gi = (wb - 99) * 256 + tid;       // < 9216
        int L = gi / 2304, r = gi - L * 2304;
        int tap = r >> 8, ci = (r >> 4) & 15, co = r & 15;
        int kz = tap / 3, ky = tap % 3;
        float s = 0.f;
#pragma unroll
        for (int kx = 0; kx < 3; kx++)
            s += ldin(WS[L], (co * 16 + ci) * 27 + kz * 9 + ky * 3 + kx, bf);
        w2d[gi] = s;
    }
}

// ---------------------------------------------------------------------------
// Fused layer. Blocks 0..255: interior 2D conv (block = (d, y-half of 64)).
// Blocks 256..1279: mini MFMA conv ((z, yt), wave = 4y). Fused IN stats.
// MODE 0: input read raw (already-final: vol0 or materialized xb).
// MODE 1: input = relu((raw - m)*s) computed on the fly from stL sums.
//   mini columns are lane-static: REAL {0..3,8..11} from Min raw; GHOST {4,7}
//   from Iin fp32; ZERO {-1,5,6,12..15,16,17} (+ the kxs==1 pad tap).
// ---------------------------------------------------------------------------
template <int MODE>
__global__ __launch_bounds__(256) void layer_k(
    const float* __restrict__ Iin, const u16* __restrict__ Min,
    const float* __restrict__ stL,
    const float* __restrict__ w2dL, const u16* __restrict__ afragL,
    const float* __restrict__ biasL,
    float* __restrict__ Iout, u16* __restrict__ Mout,
    float* __restrict__ st_out)
{
    __shared__ float smem[5734];   // wsl 2304 | pin 3366 | sred 32 | sA 32
    const int tid = threadIdx.x;

    if (blockIdx.x < 256) {
        float* wsl  = smem;
        float* pin  = smem + 2304;
        float* sred = smem + 5670;
        float* sA   = smem + 5702;
        const int d  = blockIdx.x >> 1;
        const int y0 = (blockIdx.x & 1) * 64;
        if (tid < 32) {
            sred[tid] = 0.f;
            if (MODE == 1) {
                const float inv = 1.f / 2097152.f;
                int c = tid & 15;
                float m = stL[c] * inv;
                sA[tid] = (tid < 16) ? m : rsqrtf(stL[16 + c] * inv - m * m + 1e-5f);
            }
        }
        if (MODE == 1) __syncthreads();
        for (int i = tid; i < 2304; i += 256) wsl[i] = w2dL[i];
        for (int i = tid; i < 3168; i += 256) {
            int p = i / 1056, r = i - p * 1056;
            int row = r >> 4, c = r & 15;
            int zz = d + p - 1, gy = y0 + row - 1;
            float v = 0.f;
            if ((unsigned)zz < 128u && (unsigned)gy < 128u) {
                v = Iin[(zz * 128 + gy) * 16 + c];
                if (MODE == 1) v = fmaxf((v - sA[c]) * sA[16 + c], 0.f);
            }
            pin[p * 1122 + row * 17 + c] = v;
        }
        __syncthreads();

        const int yl = tid & 63, h = tid >> 6;
        float acc[4];
#pragma unroll
        for (int cc = 0; cc < 4; cc++) acc[cc] = biasL[h * 4 + cc];
#pragma unroll
        for (int kz = 0; kz < 3; kz++) {
#pragma unroll
            for (int ky = 0; ky < 3; ky++) {
                const float* rowb = &pin[kz * 1122 + (yl + ky) * 17];
                const float* wrow = &wsl[(kz * 3 + ky) * 256 + h * 4];
#pragma unroll
                for (int ci = 0; ci < 16; ci++) {
                    float v = rowb[ci];
#pragma unroll
                    for (int cc = 0; cc < 4; cc++)
                        acc[cc] = fmaf(v, wrow[ci * 16 + cc], acc[cc]);
                }
            }
        }
        const int e = (d * 128 + y0 + yl) * 16 + h * 4;
        *(float4*)(Iout + e) = make_float4(acc[0], acc[1], acc[2], acc[3]);
        float s[4], q[4];
#pragma unroll
        for (int cc = 0; cc < 4; cc++) { s[cc] = acc[cc]; q[cc] = acc[cc] * acc[cc]; }
#pragma unroll
        for (int off = 1; off < 64; off <<= 1) {
#pragma unroll
            for (int cc = 0; cc < 4; cc++) {
                s[cc] += __shfl_down(s[cc], off, 64);
                q[cc] += __shfl_down(q[cc], off, 64);
            }
        }
        if ((tid & 63) == 0) {
#pragma unroll
            for (int cc = 0; cc < 4; cc++) {
                atomicAdd(&sred[h * 4 + cc], s[cc]);
                atomicAdd(&sred[16 + h * 4 + cc], q[cc]);
            }
        }
        __syncthreads();
        if (tid < 32) atomicAdd(&st_out[tid], 120.f * sred[tid]);
        return;
    }

    // ---------------- mini path ----------------
    float* sred = smem;
    float* sA   = smem + 32;
    const int mb = blockIdx.x - 256;
    const int z  = mb & 127;
    const int yt = mb >> 7;
    const int l = tid & 63, w = tid >> 6;
    const int n = l & 15, g = l >> 4, h = g & 1, kxs = g >> 1;
    const int y0 = yt * 16 + w * 4;

    if (tid < 32) {
        sred[tid] = 0.f;
        if (MODE == 1) {
            const float inv = 1.f / 2097152.f;
            int c = tid & 15;
            float m = stL[c] * inv;
            sA[tid] = (tid < 16) ? m : rsqrtf(stL[16 + c] * inv - m * m + 1e-5f);
        }
    }
    float mv[8], sv[8];
    if (MODE == 1) {
        __syncthreads();
#pragma unroll
        for (int j = 0; j < 8; j++) {
            mv[j] = sA[h * 8 + j];
            sv[j] = sA[16 + h * 8 + j];
        }
    }

    s16x8 af[18];
#pragma unroll
    for (int fi = 0; fi < 18; fi++)
        af[fi] = *(const s16x8*)(afragL + (fi * 64 + l) * 8);
    f32x4 binit = *(const f32x4*)(biasL + g * 4);

    f32x4 acc[4];
#pragma unroll
    for (int yl = 0; yl < 4; yl++) acc[yl] = binit;

    const int x0c = n + kxs - 1;
    const int x1c = x0c + 2;
    // MODE 0 bounds; MODE 1 column classes (0 zero, 1 real mini, 2 ghost interior)
    const bool v0ok = (unsigned)x0c < 16u;
    const bool v1ok = (unsigned)x1c < 16u;
    const int t0 = ((x0c >= 0 && x0c <= 3) || (x0c >= 8 && x0c <= 11)) ? 1
                 : (x0c == 4 || x0c == 7) ? 2 : 0;
    const int t1 = (kxs == 1) ? 0
                 : ((x1c >= 0 && x1c <= 3) || (x1c >= 8 && x1c <= 11)) ? 1
                 : (x1c == 4 || x1c == 7) ? 2 : 0;

#pragma unroll
    for (int kz = 0; kz < 3; kz++) {
        const int gz = z + kz - 1;
        const bool zv = (unsigned)gz < 128u;
#pragma unroll
        for (int yin = 0; yin < 6; yin++) {
            const int gy = y0 + yin - 1;
            const bool rv = zv && ((unsigned)gy < 128u);
            s16x8 f0 = __builtin_bit_cast(s16x8, make_uint4(0u, 0u, 0u, 0u));
            s16x8 f1 = f0;
            if (MODE == 0) {
                const u16* rp = Min + ((((gz << 7) + gy) << 8) + h * 8);
                if (rv && v0ok) f0 = __builtin_bit_cast(s16x8, *(const uint4*)(rp + (x0c << 4)));
                if (rv && v1ok) f1 = __builtin_bit_cast(s16x8, *(const uint4*)(rp + (x1c << 4)));
            } else if (rv) {
                const u16*  rp = Min + ((((gz << 7) + gy) << 8) + h * 8);
                const float* ip = Iin + ((gz << 7) + gy) * 16 + h * 8;
                if (t0 == 1) {
                    float fr[8];
                    unpack8(*(const uint4*)(rp + (x0c << 4)), fr);
                    f0 = packnorm8(fr, mv, sv);
                } else if (t0 == 2) {
                    float fr[8];
                    float4 aa = *(const float4*)ip, bb = *(const float4*)(ip + 4);
                    fr[0]=aa.x; fr[1]=aa.y; fr[2]=aa.z; fr[3]=aa.w;
                    fr[4]=bb.x; fr[5]=bb.y; fr[6]=bb.z; fr[7]=bb.w;
                    f0 = packnorm8(fr, mv, sv);
                }
                if (t1 == 1) {
                    float fr[8];
                    unpack8(*(const uint4*)(rp + (x1c << 4)), fr);
                    f1 = packnorm8(fr, mv, sv);
                } else if (t1 == 2) {
                    float fr[8];
                    float4 aa = *(const float4*)ip, bb = *(const float4*)(ip + 4);
                    fr[0]=aa.x; fr[1]=aa.y; fr[2]=aa.z; fr[3]=aa.w;
                    fr[4]=bb.x; fr[5]=bb.y; fr[6]=bb.z; fr[7]=bb.w;
                    f1 = packnorm8(fr, mv, sv);
                }
            }
#pragma unroll
            for (int ky = 0; ky < 3; ky++) {
                const int yl = yin - ky;
                if (yl >= 0 && yl < 4) {
                    acc[yl] = __builtin_amdgcn_mfma_f32_16x16x32_bf16(af[(kz * 3 + ky) * 2],     f0, acc[yl], 0, 0, 0);
                    acc[yl] = __builtin_amdgcn_mfma_f32_16x16x32_bf16(af[(kz * 3 + ky) * 2 + 1], f1, acc[yl], 0, 0, 0);
                }
            }
        }
    }

    const float inc = (((n >> 2) & 1) == 0) ? 1.f : 0.f;
    float sr[4] = {0.f, 0.f, 0.f, 0.f}, qr[4] = {0.f, 0.f, 0.f, 0.f};
#pragma unroll
    for (int yl = 0; yl < 4; yl++) {
        const int gy = y0 + yl;
        u32 lo = (u32)f2bf(acc[yl][0]) | ((u32)f2bf(acc[yl][1]) << 16);
        u32 hi = (u32)f2bf(acc[yl][2]) | ((u32)f2bf(acc[yl][3]) << 16);
        *(uint2*)(Mout + (((z << 7) + gy) << 8) + (n << 4) + g * 4) = make_uint2(lo, hi);
#pragma unroll
        for (int r = 0; r < 4; r++) {
            sr[r] += inc * acc[yl][r];
            qr[r] = fmaf(inc * acc[yl][r], acc[yl][r], qr[r]);
        }
    }
#pragma unroll
    for (int off = 1; off < 16; off <<= 1) {
#pragma unroll
        for (int r = 0; r < 4; r++) {
            sr[r] += __shfl_down(sr[r], off, 16);
            qr[r] += __shfl_down(qr[r], off, 16);
        }
    }
    __syncthreads();
    if (n == 0) {
#pragma unroll
        for (int r = 0; r < 4; r++) {
            atomicAdd(&sred[g * 4 + r], sr[r]);
            atomicAdd(&sred[16 + g * 4 + r], qr[r]);
        }
    }
    __syncthreads();
    if (tid < 32) atomicAdd(&st_out[tid], sred[tid]);
}

// Streaming normalize with residual (xb only): r8 verbatim.
__global__ __launch_bounds__(256) void norm_k(
    const float* __restrict__ Iraw, const u16* __restrict__ Mraw,
    const void* __restrict__ proj, const float* __restrict__ stL,
    const int* __restrict__ flagp,
    float* __restrict__ Iout, u16* __restrict__ Mout)
{
    __shared__ float sA[32];
    const int bf = *flagp;
    const int d  = blockIdx.x >> 2;
    const int ys = (blockIdx.x & 3) * 32;
    const int tid = threadIdx.x;
    if (tid < 32) {
        const float inv = 1.f / 2097152.f;
        int c = tid & 15;
        float m = stL[c] * inv;
        sA[tid] = (tid < 16) ? m : rsqrtf(stL[16 + c] * inv - m * m + 1e-5f);
    }
    __syncthreads();
    for (int i = tid; i < 512; i += 256) {
        int y = ys + (i >> 4), c = i & 15;
        float res = ldin(proj, c * 16384 + d * 128 + y, bf);
        float v = fmaxf((Iraw[(d * 128 + y) * 16 + c] - sA[c]) * sA[16 + c] + res, 0.f);
        Iout[(d * 128 + y) * 16 + c] = v;
    }
    for (int i = tid; i < 1024; i += 256) {
        int y = ys + (i >> 5), x = (i >> 1) & 15, hh = i & 1;
        bool realc = (x < 4) | (x >= 8 && x < 12);
        bool ghost = (x == 4) | (x == 7);
        u32 pw[4] = {0u, 0u, 0u, 0u};
        if (realc | ghost) {
            float f[8];
            if (realc) {
                uint4 raw = *(const uint4*)(Mraw + ((d * 128 + y) << 8) + (x << 4) + hh * 8);
                unpack8(raw, f);
            } else {
#pragma unroll
                for (int j = 0; j < 8; j++)
                    f[j] = Iraw[(d * 128 + y) * 16 + hh * 8 + j];
            }
            float vals[8];
#pragma unroll
            for (int j = 0; j < 8; j++) {
                int c = hh * 8 + j;
                float res = ldin(proj, c * 16384 + d * 128 + y, bf);
                vals[j] = fmaxf((f[j] - sA[c]) * sA[16 + c] + res, 0.f);
            }
#pragma unroll
            for (int j = 0; j < 4; j++)
                pw[j] = (u32)f2bf(vals[2*j]) | ((u32)f2bf(vals[2*j+1]) << 16);
        }
        *(uint4*)(Mout + ((d * 128 + y) << 8) + (x << 4) + hh * 8) =
            make_uint4(pw[0], pw[1], pw[2], pw[3]);
    }
}

// fproj: 256 blocks = (d, y-half). vol2 = relu((y4-m)s + xb). Row sums direct;
// column partials into P/PS/P0; the 2nd block finishing a given d expands that
// d's theta=pi/2 outputs (i==0 col sums y<64 only — HW-verified fp32 quirk).
__global__ __launch_bounds__(256) void fproj_k(
    const float* __restrict__ I4, const float* __restrict__ IXB,
    const u16* __restrict__ M4, const u16* __restrict__ MXB,
    const float* __restrict__ stL, const int* __restrict__ flagp,
    void* __restrict__ out,
    float* __restrict__ P, float* __restrict__ PS, float* __restrict__ P0,
    int* __restrict__ dcnt)
{
    __shared__ float sA[32];
    __shared__ int slast;
    const int bf = *flagp;
    const int d = blockIdx.x >> 1;
    const int half = blockIdx.x & 1;
    const int tid = threadIdx.x;
    if (tid < 32) {
        const float inv = 1.f / 2097152.f;
        int c = tid & 15;
        float m = stL[c] * inv;
        sA[tid] = (tid < 16) ? m : rsqrtf(stL[16 + c] * inv - m * m + 1e-5f);
    }
    __syncthreads();

    const int yl = tid & 63, y = half * 64 + yl;
    const int h = tid >> 6, c0 = h * 4;

    float v2d[4], row[4];
    {
        const int e = (d * 128 + y) * 16 + c0;
        float4 a = *(const float4*)(I4 + e);
        float4 x = *(const float4*)(IXB + e);
        float ia[4] = {a.x, a.y, a.z, a.w};
        float xa[4] = {x.x, x.y, x.z, x.w};
#pragma unroll
        for (int cc = 0; cc < 4; cc++) {
            int c = c0 + cc;
            v2d[cc] = fmaxf((ia[cc] - sA[c]) * sA[16 + c] + xa[cc], 0.f);
            row[cc] = 120.f * v2d[cc];
        }
    }
    float colp[8][4];
#pragma unroll
    for (int j = 0; j < 8; j++) {
        const int m = (j < 4) ? j : j + 4;
        const int e = ((d * 128 + y) << 8) + (m << 4) + c0;
        float f4[4], fx[4];
        unpack4(*(const uint2*)(M4 + e), f4);
        unpack4(*(const uint2*)(MXB + e), fx);
#pragma unroll
        for (int cc = 0; cc < 4; cc++) {
            int c = c0 + cc;
            float v = fmaxf((f4[cc] - sA[c]) * sA[16 + c] + fx[cc], 0.f);
            row[cc] += v;
            colp[j][cc] = v;
        }
    }
#pragma unroll
    for (int cc = 0; cc < 4; cc++) {
        int oi = ((c0 + cc) * 2) * 16384 + d * 128 + y;
        if (bf) ((u16*)out)[oi] = f2bf(row[cc]); else ((float*)out)[oi] = row[cc];
    }
#pragma unroll
    for (int off = 1; off < 64; off <<= 1) {
#pragma unroll
        for (int cc = 0; cc < 4; cc++) {
            v2d[cc] += __shfl_down(v2d[cc], off, 64);
#pragma unroll
            for (int j = 0; j < 8; j++)
                colp[j][cc] += __shfl_down(colp[j][cc], off, 64);
        }
    }
    if (yl == 0) {
#pragma unroll
        for (int cc = 0; cc < 4; cc++) {
            atomicAdd(&PS[d * 16 + c0 + cc], v2d[cc]);
#pragma unroll
            for (int j = 0; j < 8; j++)
                atomicAdd(&P[(d * 8 + j) * 16 + c0 + cc], colp[j][cc]);
            if (half == 0) P0[d * 16 + c0 + cc] = colp[0][cc];
        }
    }

    // last-block-per-d expansion (old fproj2), release/acquire via fences
    __threadfence();
    __syncthreads();
    if (tid == 0) slast = (atomicAdd(&dcnt[d], 1) == 1) ? 1 : 0;
    __syncthreads();
    if (slast) {
        __threadfence();
        for (int i = tid; i < 2048; i += 256) {
            int c = i >> 7, u = i & 127;
            float v;
            if (u == 0)        v = P0[d * 16 + c];
            else if (u < 4)    v = P[(d * 8 + u) * 16 + c];
            else if (u >= 124) v = P[(d * 8 + (u - 120)) * 16 + c];
            else               v = PS[d * 16 + c];
            int oi = (c * 2 + 1) * 16384 + d * 128 + u;
            if (bf) ((u16*)out)[oi] = f2bf(v); else ((float*)out)[oi] = v;
        }
    }
}

extern "C" void kernel_launch(void* const* d_in, const int* in_sizes, int n_in,
                              void* d_out, int out_size, void* d_ws, size_t ws_size,
                              hipStream_t stream)
{
    if (ws_size < WS_NEED) {
        sentinel_k<<<(out_size + 255) / 256, 256, 0, stream>>>((u16*)d_out, out_size);
        return;
    }
    const void* proj = d_in[0];
    const void* w1 = d_in[1]; const void* b1 = d_in[2];
    const void* w2 = d_in[3]; const void* b2 = d_in[4];
    const void* w3 = d_in[5]; const void* b3 = d_in[6];
    const void* w4 = d_in[7]; const void* b4 = d_in[8];

    float* I_A  = (float*)d_ws;                 // vol0 interior
    float* I1   = I_A  + IN_ELEMS;              // y1 raw
    float* I2   = I1   + IN_ELEMS;              // y2 raw (kept for xb)
    float* I3   = I2   + IN_ELEMS;              // y3 raw
    float* I4   = I3   + IN_ELEMS;              // y4 raw
    float* I_XB = I4   + IN_ELEMS;              // xb
    u16*   M_A  = (u16*)(I_XB + IN_ELEMS);
    u16*   M1   = M_A + MN_ELEMS;
    u16*   M2   = M1  + MN_ELEMS;
    u16*   M3   = M2  + MN_ELEMS;
    u16*   M4   = M3  + MN_ELEMS;
    u16*   M_XB = M4  + MN_ELEMS;
    float* st    = (float*)(M_XB + MN_ELEMS);   // 256
    int*   flag  = (int*)(st + 256);            // 16
    float* biasf = (float*)(flag + 16);         // 64
    float* w2d   = biasf + 64;                  // 9216
    float* P     = w2d + 9216;                  // 16384
    float* PS    = P + 16384;                   // 2048
    float* P0    = PS + 2048;                   // 2048
    int*   dcnt  = (int*)(P0 + 2048);           // 128
    u16*   afrag = (u16*)(dcnt + 128);          // 36864

    dim3 cb(256);
    prep_all_k<<<647, cb, 0, stream>>>(proj, w1, w2, w3, w4, b1, b2, b3, b4,
                                       st, flag, biasf, w2d, P, dcnt, afrag,
                                       I_A, M_A);
    // L1: input = vol0 (raw)
    layer_k<0><<<1280, cb, 0, stream>>>(I_A, M_A, st,
                                        w2d + 0, afrag + 0, biasf + 0,
                                        I1, M1, st + 0);
    // L2: input = relu(IN(y1)) fused
    layer_k<1><<<1280, cb, 0, stream>>>(I1, M1, st + 0,
                                        w2d + 2304, afrag + 9216, biasf + 16,
                                        I2, M2, st + 64);
    // xb = relu(IN(y2) + vol0) materialized (also feeds fproj)
    norm_k<<<512, cb, 0, stream>>>(I2, M2, proj, st + 64, flag, I_XB, M_XB);
    // L3: input = xb (raw)
    layer_k<0><<<1280, cb, 0, stream>>>(I_XB, M_XB, st,
                                        w2d + 4608, afrag + 18432, biasf + 32,
                                        I3, M3, st + 128);
    // L4: input = relu(IN(y3)) fused
    layer_k<1><<<1280, cb, 0, stream>>>(I3, M3, st + 128,
                                        w2d + 6912, afrag + 27648, biasf + 48,
                                        I4, M4, st + 192);
    // projection (row sums + column partials + in-dispatch expansion)
    fproj_k<<<256, cb, 0, stream>>>(I4, I_XB, M4, M_XB, st + 192, flag, d_out,
                                    P, PS, P0, dcnt);
}

// Round 11
// 259.091 us; speedup vs baseline: 1.1629x; 1.1629x over previous
//
#include <hip/hip_runtime.h>

// GeometryTransformation: backproject(theta=0) -> 2x resblock(conv3d 16->16 3^3,
// InstanceNorm, ReLU, residual) -> forward-project at theta in {0, pi/2}.
//
// Round-11: best-proven composition. r8's pipeline (x-constancy factorization:
// interior 2D field fp32 + width-16 boundary mini volume bf16; pure MODE-0
// MFMA layer kernel; separate streaming norm) + r10's two verified dispatch
// merges (prep_all_k, fproj in-dispatch expansion). 9 dispatches total.
// r10 lesson (repeat of r4): do NOT fuse per-fragment normalize into the MFMA
// inner loop — VALUBusy 46%, +30us/dispatch. Keep the hot kernel pure.
// Math identical to rounds 8/10 (passed, absmax 4.0).

typedef unsigned short u16;
typedef unsigned int   u32;
using s16x8 = __attribute__((ext_vector_type(8))) short;
using f32x4 = __attribute__((ext_vector_type(4))) float;

#define IN_ELEMS 262144        // 128*128*16 fp32 interior
#define MN_ELEMS 4194304       // 128*128*16*16 u16 mini
#define WS_NEED  28506944ull

__device__ __forceinline__ float bf2f(u16 h) {
    union { u32 u; float f; } v; v.u = ((u32)h) << 16; return v.f;
}
__device__ __forceinline__ u16 f2bf(float f) {
    union { float f; u32 u; } v; v.f = f;
    u32 u = v.u;
    return (u16)((u + 0x7fffu + ((u >> 16) & 1u)) >> 16);
}
__device__ __forceinline__ float ldin(const void* p, int i, int bf) {
    return bf ? bf2f(((const u16*)p)[i]) : ((const float*)p)[i];
}
__device__ __forceinline__ u16 ldbf(const void* p, int i, int bf) {
    return bf ? ((const u16*)p)[i] : f2bf(((const float*)p)[i]);
}
__device__ __forceinline__ void unpack8(uint4 a, float* f) {
    u32 w[4] = {a.x, a.y, a.z, a.w};
#pragma unroll
    for (int i = 0; i < 4; i++) {
        f[2*i]   = bf2f((u16)(w[i] & 0xffff));
        f[2*i+1] = bf2f((u16)(w[i] >> 16));
    }
}
__device__ __forceinline__ void unpack4(uint2 a, float* f) {
    f[0] = bf2f((u16)(a.x & 0xffff)); f[1] = bf2f((u16)(a.x >> 16));
    f[2] = bf2f((u16)(a.y & 0xffff)); f[3] = bf2f((u16)(a.y >> 16));
}

__global__ void sentinel_k(u16* __restrict__ out, int n)
{
    int i = blockIdx.x * 256 + threadIdx.x;
    if (i < n) out[i] = 0x4640;
}

// ---------------------------------------------------------------------------
// Merged prep (r10-proven): 647 blocks.
//  bid 0..511 : layer-0 state (interior I0 fp32 + mini M0, cols {0..4,7,8..11}
//               = proj, rest 0)
//  wb = bid-512:
//   0..17  : afrag[L][fi][lane][8]  (lane-ordered MFMA A operands)
//   18     : st zero + flag + biasf + dcnt zero
//   19..98 : zero P/PS/P0 (20480 floats contiguous from P)
//   99..134: w2d[L][tap9][ci][co] kx-summed fp32
// ---------------------------------------------------------------------------
__global__ __launch_bounds__(256) void prep_all_k(
    const void* __restrict__ proj,
    const void* __restrict__ w1, const void* __restrict__ w2,
    const void* __restrict__ w3, const void* __restrict__ w4,
    const void* __restrict__ b1, const void* __restrict__ b2,
    const void* __restrict__ b3, const void* __restrict__ b4,
    float* __restrict__ st, int* __restrict__ flag, float* __restrict__ biasf,
    float* __restrict__ w2d, float* __restrict__ pz, int* __restrict__ dcnt,
    u16* __restrict__ afrag, float* __restrict__ I0, u16* __restrict__ M0)
{
    const int tid = threadIdx.x;
    const u16* pp = (const u16*)w1;
    int cnt = 0;
    for (int i = 0; i < 32; i++) {
        int e = (pp[2 * i] >> 7) & 0xFF;
        if (e >= 64 && e <= 130) cnt++;
    }
    const int bf = (cnt >= 24) ? 1 : 0;

    if (blockIdx.x < 512) {
        const int d = blockIdx.x >> 2;
        const int ys = (blockIdx.x & 3) * 32;
        for (int i = tid; i < 512; i += 256) {
            int y = ys + (i >> 4), c = i & 15;
            I0[(d * 128 + y) * 16 + c] = ldin(proj, c * 16384 + d * 128 + y, bf);
        }
        for (int i = tid; i < 1024; i += 256) {
            int y = ys + (i >> 5), x = (i >> 1) & 15, hh = i & 1;
            bool on = (x <= 4) | (x == 7) | (x >= 8 && x < 12);
            u32 pw[4] = {0u, 0u, 0u, 0u};
            if (on) {
#pragma unroll
                for (int j = 0; j < 4; j++) {
                    int c0 = hh * 8 + 2 * j;
                    u16 a = f2bf(ldin(proj, c0 * 16384 + d * 128 + y, bf));
                    u16 b = f2bf(ldin(proj, (c0 + 1) * 16384 + d * 128 + y, bf));
                    pw[j] = (u32)a | ((u32)b << 16);
                }
            }
            *(uint4*)(M0 + ((d * 128 + y) << 8) + (x << 4) + hh * 8) =
                make_uint4(pw[0], pw[1], pw[2], pw[3]);
        }
        return;
    }

    const void* WS[4] = {w1, w2, w3, w4};
    const void* BS[4] = {b1, b2, b3, b4};
    const int wb = blockIdx.x - 512;
    if (wb < 18) {
        int gi = wb * 256 + tid;              // < 4608
        int L = gi / 1152, r = gi - L * 1152;
        int fi = r >> 6, l = r & 63;
        int kzky = fi >> 1, grp = fi & 1;
        int kz = kzky / 3, ky = kzky % 3;
        int n = l & 15, g = l >> 4, h = g & 1, kxs = g >> 1;
        int kx = grp * 2 + kxs;
        u16 v[8];
#pragma unroll
        for (int e = 0; e < 8; e++) {
            int ci = h * 8 + e;
            v[e] = (kx <= 2) ? ldbf(WS[L], n * 432 + ci * 27 + kz * 9 + ky * 3 + kx, bf)
                             : (u16)0;
        }
#pragma unroll
        for (int e = 0; e < 8; e++) afrag[gi * 8 + e] = v[e];
    } else if (wb == 18) {
        st[tid] = 0.f;
        if (tid == 0) *flag = bf;
        if (tid < 64) biasf[tid] = ldin(BS[tid >> 4], tid & 15, bf);
        if (tid < 128) dcnt[tid] = 0;
    } else if (wb < 99) {
        int i = (wb - 19) * 256 + tid;        // P(16384)+PS(2048)+P0(2048)
        pz[i] = 0.f;
    } else {
        int gi = (wb - 99) * 256 + tid;       // < 9216
        int L = gi / 2304, r = gi - L * 2304;
        int tap = r >> 8, ci = (r >> 4) & 15, co = r & 15;
        int kz = tap / 3, ky = tap % 3;
        float s = 0.f;
#pragma unroll
        for (int kx = 0; kx < 3; kx++)
            s += ldin(WS[L], (co * 16 + ci) * 27 + kz * 9 + ky * 3 + kx, bf);
        w2d[gi] = s;
    }
}

// ---------------------------------------------------------------------------
// Fused layer (r8 verbatim — pure, input pre-normalized). Blocks 0..255:
// interior 2D conv (block=(d, y-half of 64)). Blocks 256..1279: mini MFMA conv
// ((z,yt), wave = 4y, A-frags 18 coalesced dwordx4, B-frags direct-global
// predicated). Both accumulate InstanceNorm stats (interior weighted 120x).
// ---------------------------------------------------------------------------
__global__ __launch_bounds__(256) void layer_k(
    const float* __restrict__ Iin, const u16* __restrict__ Min,
    const float* __restrict__ w2dL, const u16* __restrict__ afragL,
    const float* __restrict__ biasL,
    float* __restrict__ Iout, u16* __restrict__ Mout,
    float* __restrict__ st_out)
{
    __shared__ float smem[5702];   // interior: wsl 2304 | pin 3366 | sred 32
    const int tid = threadIdx.x;

    if (blockIdx.x < 256) {
        float* wsl  = smem;
        float* pin  = smem + 2304;
        float* sred = smem + 5670;
        const int d  = blockIdx.x >> 1;
        const int y0 = (blockIdx.x & 1) * 64;
        if (tid < 32) sred[tid] = 0.f;
        for (int i = tid; i < 2304; i += 256) wsl[i] = w2dL[i];
        for (int i = tid; i < 3168; i += 256) {
            int p = i / 1056, r = i - p * 1056;
            int row = r >> 4, c = r & 15;
            int zz = d + p - 1, gy = y0 + row - 1;
            float v = 0.f;
            if ((unsigned)zz < 128u && (unsigned)gy < 128u)
                v = Iin[(zz * 128 + gy) * 16 + c];
            pin[p * 1122 + row * 17 + c] = v;
        }
        __syncthreads();

        const int yl = tid & 63, h = tid >> 6;
        float acc[4];
#pragma unroll
        for (int cc = 0; cc < 4; cc++) acc[cc] = biasL[h * 4 + cc];
#pragma unroll
        for (int kz = 0; kz < 3; kz++) {
#pragma unroll
            for (int ky = 0; ky < 3; ky++) {
                const float* rowb = &pin[kz * 1122 + (yl + ky) * 17];
                const float* wrow = &wsl[(kz * 3 + ky) * 256 + h * 4];
#pragma unroll
                for (int ci = 0; ci < 16; ci++) {
                    float v = rowb[ci];
#pragma unroll
                    for (int cc = 0; cc < 4; cc++)
                        acc[cc] = fmaf(v, wrow[ci * 16 + cc], acc[cc]);
                }
            }
        }
        const int e = (d * 128 + y0 + yl) * 16 + h * 4;
        *(float4*)(Iout + e) = make_float4(acc[0], acc[1], acc[2], acc[3]);
        float s[4], q[4];
#pragma unroll
        for (int cc = 0; cc < 4; cc++) { s[cc] = acc[cc]; q[cc] = acc[cc] * acc[cc]; }
#pragma unroll
        for (int off = 1; off < 64; off <<= 1) {
#pragma unroll
            for (int cc = 0; cc < 4; cc++) {
                s[cc] += __shfl_down(s[cc], off, 64);
                q[cc] += __shfl_down(q[cc], off, 64);
            }
        }
        if ((tid & 63) == 0) {
#pragma unroll
            for (int cc = 0; cc < 4; cc++) {
                atomicAdd(&sred[h * 4 + cc], s[cc]);
                atomicAdd(&sred[16 + h * 4 + cc], q[cc]);
            }
        }
        __syncthreads();
        if (tid < 32) atomicAdd(&st_out[tid], 120.f * sred[tid]);
        return;
    }

    // ---------------- mini path ----------------
    float* sred = smem;
    const int mb = blockIdx.x - 256;
    const int z  = mb & 127;
    const int yt = mb >> 7;
    const int l = tid & 63, w = tid >> 6;
    const int n = l & 15, g = l >> 4, h = g & 1, kxs = g >> 1;
    const int y0 = yt * 16 + w * 4;

    if (tid < 32) sred[tid] = 0.f;

    s16x8 af[18];
#pragma unroll
    for (int fi = 0; fi < 18; fi++)
        af[fi] = *(const s16x8*)(afragL + (fi * 64 + l) * 8);
    f32x4 binit = *(const f32x4*)(biasL + g * 4);

    f32x4 acc[4];
#pragma unroll
    for (int yl = 0; yl < 4; yl++) acc[yl] = binit;

    const int x0c = n + kxs - 1;
    const int x1c = x0c + 2;
    const bool v0ok = (unsigned)x0c < 16u;
    const bool v1ok = (unsigned)x1c < 16u;

#pragma unroll
    for (int kz = 0; kz < 3; kz++) {
        const int gz = z + kz - 1;
        const bool zv = (unsigned)gz < 128u;
#pragma unroll
        for (int yin = 0; yin < 6; yin++) {
            const int gy = y0 + yin - 1;
            const bool rv = zv && ((unsigned)gy < 128u);
            const u16* rp = Min + ((((gz << 7) + gy) << 8) + h * 8);
            uint4 q0 = make_uint4(0u, 0u, 0u, 0u);
            uint4 q1 = make_uint4(0u, 0u, 0u, 0u);
            if (rv && v0ok) q0 = *(const uint4*)(rp + (x0c << 4));
            if (rv && v1ok) q1 = *(const uint4*)(rp + (x1c << 4));
            s16x8 f0 = __builtin_bit_cast(s16x8, q0);
            s16x8 f1 = __builtin_bit_cast(s16x8, q1);
#pragma unroll
            for (int ky = 0; ky < 3; ky++) {
                const int yl = yin - ky;
                if (yl >= 0 && yl < 4) {
                    acc[yl] = __builtin_amdgcn_mfma_f32_16x16x32_bf16(af[(kz * 3 + ky) * 2],     f0, acc[yl], 0, 0, 0);
                    acc[yl] = __builtin_amdgcn_mfma_f32_16x16x32_bf16(af[(kz * 3 + ky) * 2 + 1], f1, acc[yl], 0, 0, 0);
                }
            }
        }
    }

    const float inc = (((n >> 2) & 1) == 0) ? 1.f : 0.f;
    float sr[4] = {0.f, 0.f, 0.f, 0.f}, qr[4] = {0.f, 0.f, 0.f, 0.f};
#pragma unroll
    for (int yl = 0; yl < 4; yl++) {
        const int gy = y0 + yl;
        u32 lo = (u32)f2bf(acc[yl][0]) | ((u32)f2bf(acc[yl][1]) << 16);
        u32 hi = (u32)f2bf(acc[yl][2]) | ((u32)f2bf(acc[yl][3]) << 16);
        *(uint2*)(Mout + (((z << 7) + gy) << 8) + (n << 4) + g * 4) = make_uint2(lo, hi);
#pragma unroll
        for (int r = 0; r < 4; r++) {
            sr[r] += inc * acc[yl][r];
            qr[r] = fmaf(inc * acc[yl][r], acc[yl][r], qr[r]);
        }
    }
#pragma unroll
    for (int off = 1; off < 16; off <<= 1) {
#pragma unroll
        for (int r = 0; r < 4; r++) {
            sr[r] += __shfl_down(sr[r], off, 16);
            qr[r] += __shfl_down(qr[r], off, 16);
        }
    }
    __syncthreads();
    if (n == 0) {
#pragma unroll
        for (int r = 0; r < 4; r++) {
            atomicAdd(&sred[g * 4 + r], sr[r]);
            atomicAdd(&sred[16 + g * 4 + r], qr[r]);
        }
    }
    __syncthreads();
    if (tid < 32) atomicAdd(&st_out[tid], sred[tid]);
}

// Streaming normalize (r8 verbatim, 512 blocks): m,s from raw sums; RES adds
// vol0(=proj broadcast). Rebuilds interior fp32 + mini bf16 (ghosts cols 4/7).
template <int RES>
__global__ __launch_bounds__(256) void norm_k(
    const float* __restrict__ Iraw, const u16* __restrict__ Mraw,
    const void* __restrict__ proj, const float* __restrict__ stL,
    const int* __restrict__ flagp,
    float* __restrict__ Iout, u16* __restrict__ Mout)
{
    __shared__ float sA[32];
    const int bf = *flagp;
    const int d  = blockIdx.x >> 2;
    const int ys = (blockIdx.x & 3) * 32;
    const int tid = threadIdx.x;
    if (tid < 32) {
        const float inv = 1.f / 2097152.f;
        int c = tid & 15;
        float m = stL[c] * inv;
        sA[tid] = (tid < 16) ? m : rsqrtf(stL[16 + c] * inv - m * m + 1e-5f);
    }
    __syncthreads();
    for (int i = tid; i < 512; i += 256) {
        int y = ys + (i >> 4), c = i & 15;
        float res = RES ? ldin(proj, c * 16384 + d * 128 + y, bf) : 0.f;
        float v = fmaxf((Iraw[(d * 128 + y) * 16 + c] - sA[c]) * sA[16 + c] + res, 0.f);
        Iout[(d * 128 + y) * 16 + c] = v;
    }
    for (int i = tid; i < 1024; i += 256) {
        int y = ys + (i >> 5), x = (i >> 1) & 15, hh = i & 1;
        bool realc = (x < 4) | (x >= 8 && x < 12);
        bool ghost = (x == 4) | (x == 7);
        u32 pw[4] = {0u, 0u, 0u, 0u};
        if (realc | ghost) {
            float f[8];
            if (realc) {
                uint4 raw = *(const uint4*)(Mraw + ((d * 128 + y) << 8) + (x << 4) + hh * 8);
                unpack8(raw, f);
            } else {
#pragma unroll
                for (int j = 0; j < 8; j++)
                    f[j] = Iraw[(d * 128 + y) * 16 + hh * 8 + j];
            }
            float vals[8];
#pragma unroll
            for (int j = 0; j < 8; j++) {
                int c = hh * 8 + j;
                float res = RES ? ldin(proj, c * 16384 + d * 128 + y, bf) : 0.f;
                vals[j] = fmaxf((f[j] - sA[c]) * sA[16 + c] + res, 0.f);
            }
#pragma unroll
            for (int j = 0; j < 4; j++)
                pw[j] = (u32)f2bf(vals[2*j]) | ((u32)f2bf(vals[2*j+1]) << 16);
        }
        *(uint4*)(Mout + ((d * 128 + y) << 8) + (x << 4) + hh * 8) =
            make_uint4(pw[0], pw[1], pw[2], pw[3]);
    }
}

// fproj (r10-proven): 256 blocks = (d, y-half). vol2 = relu((y4-m)s + xb).
// Row sums direct; column partials into P/PS/P0; 2nd block per d expands the
// theta=pi/2 outputs (i==0 col sums y<64 only — HW-verified fp32 quirk).
__global__ __launch_bounds__(256) void fproj_k(
    const float* __restrict__ I4, const float* __restrict__ IXB,
    const u16* __restrict__ M4, const u16* __restrict__ MXB,
    const float* __restrict__ stL, const int* __restrict__ flagp,
    void* __restrict__ out,
    float* __restrict__ P, float* __restrict__ PS, float* __restrict__ P0,
    int* __restrict__ dcnt)
{
    __shared__ float sA[32];
    __shared__ int slast;
    const int bf = *flagp;
    const int d = blockIdx.x >> 1;
    const int half = blockIdx.x & 1;
    const int tid = threadIdx.x;
    if (tid < 32) {
        const float inv = 1.f / 2097152.f;
        int c = tid & 15;
        float m = stL[c] * inv;
        sA[tid] = (tid < 16) ? m : rsqrtf(stL[16 + c] * inv - m * m + 1e-5f);
    }
    __syncthreads();

    const int yl = tid & 63, y = half * 64 + yl;
    const int h = tid >> 6, c0 = h * 4;

    float v2d[4], row[4];
    {
        const int e = (d * 128 + y) * 16 + c0;
        float4 a = *(const float4*)(I4 + e);
        float4 x = *(const float4*)(IXB + e);
        float ia[4] = {a.x, a.y, a.z, a.w};
        float xa[4] = {x.x, x.y, x.z, x.w};
#pragma unroll
        for (int cc = 0; cc < 4; cc++) {
            int c = c0 + cc;
            v2d[cc] = fmaxf((ia[cc] - sA[c]) * sA[16 + c] + xa[cc], 0.f);
            row[cc] = 120.f * v2d[cc];
        }
    }
    float colp[8][4];
#pragma unroll
    for (int j = 0; j < 8; j++) {
        const int m = (j < 4) ? j : j + 4;
        const int e = ((d * 128 + y) << 8) + (m << 4) + c0;
        float f4[4], fx[4];
        unpack4(*(const uint2*)(M4 + e), f4);
        unpack4(*(const uint2*)(MXB + e), fx);
#pragma unroll
        for (int cc = 0; cc < 4; cc++) {
            int c = c0 + cc;
            float v = fmaxf((f4[cc] - sA[c]) * sA[16 + c] + fx[cc], 0.f);
            row[cc] += v;
            colp[j][cc] = v;
        }
    }
#pragma unroll
    for (int cc = 0; cc < 4; cc++) {
        int oi = ((c0 + cc) * 2) * 16384 + d * 128 + y;
        if (bf) ((u16*)out)[oi] = f2bf(row[cc]); else ((float*)out)[oi] = row[cc];
    }
#pragma unroll
    for (int off = 1; off < 64; off <<= 1) {
#pragma unroll
        for (int cc = 0; cc < 4; cc++) {
            v2d[cc] += __shfl_down(v2d[cc], off, 64);
#pragma unroll
            for (int j = 0; j < 8; j++)
                colp[j][cc] += __shfl_down(colp[j][cc], off, 64);
        }
    }
    if (yl == 0) {
#pragma unroll
        for (int cc = 0; cc < 4; cc++) {
            atomicAdd(&PS[d * 16 + c0 + cc], v2d[cc]);
#pragma unroll
            for (int j = 0; j < 8; j++)
                atomicAdd(&P[(d * 8 + j) * 16 + c0 + cc], colp[j][cc]);
            if (half == 0) P0[d * 16 + c0 + cc] = colp[0][cc];
        }
    }

    __threadfence();
    __syncthreads();
    if (tid == 0) slast = (atomicAdd(&dcnt[d], 1) == 1) ? 1 : 0;
    __syncthreads();
    if (slast) {
        __threadfence();
        for (int i = tid; i < 2048; i += 256) {
            int c = i >> 7, u = i & 127;
            float v;
            if (u == 0)        v = P0[d * 16 + c];
            else if (u < 4)    v = P[(d * 8 + u) * 16 + c];
            else if (u >= 124) v = P[(d * 8 + (u - 120)) * 16 + c];
            else               v = PS[d * 16 + c];
            int oi = (c * 2 + 1) * 16384 + d * 128 + u;
            if (bf) ((u16*)out)[oi] = f2bf(v); else ((float*)out)[oi] = v;
        }
    }
}

extern "C" void kernel_launch(void* const* d_in, const int* in_sizes, int n_in,
                              void* d_out, int out_size, void* d_ws, size_t ws_size,
                              hipStream_t stream)
{
    if (ws_size < WS_NEED) {
        sentinel_k<<<(out_size + 255) / 256, 256, 0, stream>>>((u16*)d_out, out_size);
        return;
    }
    const void* proj = d_in[0];
    const void* w1 = d_in[1]; const void* b1 = d_in[2];
    const void* w2 = d_in[3]; const void* b2 = d_in[4];
    const void* w3 = d_in[5]; const void* b3 = d_in[6];
    const void* w4 = d_in[7]; const void* b4 = d_in[8];

    float* I_A  = (float*)d_ws;                 // vol0 / n1 / n3 (rotating)
    float* I_B  = I_A + IN_ELEMS;               // raw conv outputs
    float* I_XB = I_B + IN_ELEMS;               // xb (kept for fproj)
    u16*   M_A  = (u16*)(I_XB + IN_ELEMS);
    u16*   M_B  = M_A + MN_ELEMS;
    u16*   M_XB = M_B + MN_ELEMS;
    float* st    = (float*)(M_XB + MN_ELEMS);   // 256
    int*   flag  = (int*)(st + 256);            // 16
    float* biasf = (float*)(flag + 16);         // 64
    float* w2d   = biasf + 64;                  // 9216
    float* P     = w2d + 9216;                  // 16384
    float* PS    = P + 16384;                   // 2048
    float* P0    = PS + 2048;                   // 2048
    int*   dcnt  = (int*)(P0 + 2048);           // 128
    u16*   afrag = (u16*)(dcnt + 128);          // 36864

    dim3 cb(256);
    prep_all_k<<<647, cb, 0, stream>>>(proj, w1, w2, w3, w4, b1, b2, b3, b4,
                                       st, flag, biasf, w2d, P, dcnt, afrag,
                                       I_A, M_A);
    // L1
    layer_k<<<1280, cb, 0, stream>>>(I_A, M_A, w2d + 0, afrag + 0, biasf + 0,
                                     I_B, M_B, st + 0);
    norm_k<0><<<512, cb, 0, stream>>>(I_B, M_B, proj, st + 0, flag, I_A, M_A);
    // L2
    layer_k<<<1280, cb, 0, stream>>>(I_A, M_A, w2d + 2304, afrag + 9216, biasf + 16,
                                     I_B, M_B, st + 64);
    norm_k<1><<<512, cb, 0, stream>>>(I_B, M_B, proj, st + 64, flag, I_XB, M_XB);
    // L3
    layer_k<<<1280, cb, 0, stream>>>(I_XB, M_XB, w2d + 4608, afrag + 18432, biasf + 32,
                                     I_B, M_B, st + 128);
    norm_k<0><<<512, cb, 0, stream>>>(I_B, M_B, proj, st + 128, flag, I_A, M_A);
    // L4
    layer_k<<<1280, cb, 0, stream>>>(I_A, M_A, w2d + 6912, afrag + 27648, biasf + 48,
                                     I_B, M_B, st + 192);
    // projection (row sums + column partials + in-dispatch expansion)
    fproj_k<<<256, cb, 0, stream>>>(I_B, I_XB, M_B, M_XB, st + 192, flag, d_out,
                                    P, PS, P0, dcnt);
}